// Round 11
// baseline (392.957 us; speedup 1.0000x reference)
//
#include <hip/hip_runtime.h>

typedef __bf16 bf16;
typedef __bf16 bf16x8 __attribute__((ext_vector_type(8)));
typedef float f32x4 __attribute__((ext_vector_type(4)));

#define HD 768
#define ELTS 6291456   // 8*1024*768
#define WELTS 589824   // 768*768

__device__ __forceinline__ void gld_lds16(const bf16* g, bf16* l) {
  __builtin_amdgcn_global_load_lds((const __attribute__((address_space(1))) void*)g,
                                   (__attribute__((address_space(3))) void*)l, 16, 0, 0);
}

__device__ __forceinline__ float rdscalar(const void* p, int f) {
  return f ? (float)((const bf16*)p)[0] : ((const float*)p)[0];
}

__device__ __forceinline__ float exp2fast(float x) {
#if __has_builtin(__builtin_amdgcn_exp2f)
  return __builtin_amdgcn_exp2f(x);
#else
  return __builtin_exp2f(x);
#endif
}

__global__ void probe_dtype(const unsigned int* __restrict__ x, int* flag) {
  const int t = threadIdx.x;  // 64 threads
  int bad = 0;
#pragma unroll
  for (int i = 0; i < 4; ++i) {
    unsigned int wd = x[t * 4 + i];
    unsigned int e0 = (wd >> 7) & 0xFF;
    unsigned int e1 = (wd >> 23) & 0xFF;
    bad += (e0 >= 134) + (e1 >= 134);
  }
  unsigned long long m = __ballot(bad > 0);
  if (t == 0) *flag = (m == 0ULL) ? 1 : 0;   // 1 = bf16 inputs
}

// fp32 -> bf16 conversion (flag==0 only). QKV-side destinations live in d_out
// (consumed ONLY by the QKV GEMM, stream-ordered before the projection GEMM
// writes d_out). Projection W/bias destinations live in spare workspace when
// ws_size permits.
struct CvtArgs {
  const float* src[20];
  bf16* dst[20];
  int n[20];
  const int* flag;
};
__global__ __launch_bounds__(256) void convert_inputs(CvtArgs a) {
  if (*a.flag) return;
  const int seg = blockIdx.y;
  const float* s = a.src[seg];
  bf16* d = a.dst[seg];
  const int n4 = a.n[seg] >> 2;
  for (int i = blockIdx.x * blockDim.x + threadIdx.x; i < n4; i += gridDim.x * blockDim.x) {
    f32x4 v = *(const f32x4*)(s + i * 4);
    bf16 o[4];
#pragma unroll
    for (int e = 0; e < 4; ++e) o[e] = (bf16)v[e];
    *(unsigned long long*)(d + i * 4) = *(unsigned long long*)o;
  }
}

struct GemmArgs {
  const void* A[6];     // bf16 when flag==1
  const void* Ac[6];    // bf16 when flag==0 (converted / internal)
  const void* W[6];     // bf16 when flag==1
  const void* Wc[6];    // flag==0: bf16 converted (ext_w=0) or fp32 original (ext_w=1)
  const void* bias[6];  // bf16 when flag==1
  const void* biasc[6]; // flag==0: bf16 converted (ext_w=0) or fp32 original (ext_w=1)
  const void* s0[6];
  const void* s1[6];
  void* C[6];
  float cmul[6];        // epilogue scale on (acc + bias)
  int c_fixed[6];       // 1: C always internal bf16; 0: C dtype follows flag
  int vt[6];            // 1: write C transposed per-head: [b][h][d=64][s=1024]
  int ext_w[6];         // 1: when flag==0, W/bias are fp32 -> convert in-kernel
  long long out_elem_off[6];
  const int* flag;
};

// C[M=8192, N=768] = (A[M,768] @ W[N,768]^T + bias*bscale) * cmul
// BK=64 k-steps, XOR-swizzled LDS staging (conflict-free fragment reads).
__global__ __launch_bounds__(256) void gemm_bt(GemmArgs args) {
  const int g = blockIdx.z;
  const int f = *args.flag;
  const bool c_bf = args.c_fixed[g] || f;
  const bool w_f32 = (!f) && args.ext_w[g];
  const bf16* __restrict__ A = (const bf16*)(f ? args.A[g] : args.Ac[g]);
  const void* __restrict__ Wp = f ? args.W[g] : args.Wc[g];
  const void* __restrict__ bias = f ? args.bias[g] : args.biasc[g];
  bf16* Cb = (bf16*)args.C[g] + args.out_elem_off[g];
  float* Cf = (float*)args.C[g] + args.out_elem_off[g];
  float bscale = 1.0f;
  if (args.s0[g]) bscale = rdscalar(args.s0[g], f) + rdscalar(args.s1[g], f);
  const float cmul = args.cmul[g];

  const int m0 = blockIdx.x * 128;
  const int n0 = blockIdx.y * 128;
  const int t = threadIdx.x;
  const int lane = t & 63;
  const int w = t >> 6;
  const int wm = (w >> 1) * 64, wn = (w & 1) * 64;

  __shared__ __attribute__((aligned(16))) bf16 As[128 * 64];
  __shared__ __attribute__((aligned(16))) bf16 Bs[128 * 64];

  f32x4 acc[4][4] = {};

  // staging map: chunk q = t + i*256 -> row = q>>3 (row&7 invariant over i),
  // slot = q&7; global col group = slot ^ (row&7); LDS dest linear.
  const int row_s = t >> 3, slot_s = t & 7;
  const int gswz = (slot_s ^ (row_s & 7)) << 3;

  const int fr = lane & 15;
  const int l4 = lane >> 4;
  // fragment read slots for the two K=32 subtiles
  const int sR0 = ((l4) ^ (fr & 7)) << 3;
  const int sR1 = ((4 + l4) ^ (fr & 7)) << 3;

  for (int kb = 0; kb < 12; ++kb) {
    const int k0 = kb * 64;
#pragma unroll
    for (int i = 0; i < 4; ++i) {
      const int row = row_s + i * 32;
      gld_lds16(A + (size_t)(m0 + row) * HD + k0 + gswz, As + (t + i * 256) * 8);
    }
    if (!w_f32) {
#pragma unroll
      for (int i = 0; i < 4; ++i) {
        const int row = row_s + i * 32;
        gld_lds16((const bf16*)Wp + (size_t)(n0 + row) * HD + k0 + gswz, Bs + (t + i * 256) * 8);
      }
    } else {
      const float* Wf = (const float*)Wp;
#pragma unroll
      for (int i = 0; i < 4; ++i) {
        const int row = row_s + i * 32;
        const size_t src = (size_t)(n0 + row) * HD + k0 + gswz;
        f32x4 u0 = *(const f32x4*)(Wf + src), u1 = *(const f32x4*)(Wf + src + 4);
        bf16x8 v;
#pragma unroll
        for (int e = 0; e < 4; ++e) { v[e] = (bf16)u0[e]; v[e + 4] = (bf16)u1[e]; }
        *(bf16x8*)(Bs + (t + i * 256) * 8) = v;
      }
    }
    __syncthreads();
#pragma unroll
    for (int kk = 0; kk < 2; ++kk) {
      const int sR = kk ? sR1 : sR0;
      bf16x8 af[4], bfr[4];
#pragma unroll
      for (int mi = 0; mi < 4; ++mi)
        af[mi] = *(const bf16x8*)(As + (wm + mi * 16 + fr) * 64 + sR);
#pragma unroll
      for (int ni = 0; ni < 4; ++ni)
        bfr[ni] = *(const bf16x8*)(Bs + (wn + ni * 16 + fr) * 64 + sR);
#pragma unroll
      for (int mi = 0; mi < 4; ++mi)
#pragma unroll
        for (int ni = 0; ni < 4; ++ni)
          acc[mi][ni] = __builtin_amdgcn_mfma_f32_16x16x32_bf16(af[mi], bfr[ni], acc[mi][ni], 0, 0, 0);
    }
    __syncthreads();
  }

  const int rq = (lane >> 4) * 4;
  const int is_vt = args.vt[g];
#pragma unroll
  for (int ni = 0; ni < 4; ++ni) {
    const int col = n0 + wn + ni * 16 + fr;
    const float bv = (w_f32 ? ((const float*)bias)[col]
                            : (float)((const bf16*)bias)[col]) * bscale;
#pragma unroll
    for (int mi = 0; mi < 4; ++mi) {
      const int row = m0 + wm + mi * 16 + rq;   // row % 4 == 0
      if (is_vt) {
        // 4 consecutive tokens (same bb, same d) -> one 8B store
        const int bb = row >> 10, s = row & 1023;
        const int hh = col >> 6, d = col & 63;
        bf16 tmp[4];
#pragma unroll
        for (int r = 0; r < 4; ++r) tmp[r] = (bf16)((acc[mi][ni][r] + bv) * cmul);
        *(unsigned long long*)(Cb + (((size_t)(bb * 12 + hh)) << 16) + (d << 10) + s) =
            *(const unsigned long long*)tmp;
      } else {
#pragma unroll
        for (int r = 0; r < 4; ++r) {
          const float val = (acc[mi][ni][r] + bv) * cmul;
          if (c_bf) Cb[(size_t)(row + r) * HD + col] = (bf16)val;
          else      Cf[(size_t)(row + r) * HD + col] = val;
        }
      }
    }
  }
}

// FUSED two-stream flash attention, SHIFT-FREE softmax — R9 structure
// (V fragments hoisted to 8 named regs, (256,3), proven 120us) with the
// K-MERGE RETRIED now that the spill mechanism is understood: R5/R6's
// merged-body regressions showed the same scratch signature R8 did
// (WRITE_SIZE 70-158MB at flat VGPR=64) — they were regalloc spills at the
// exhausted (256,4)=128-reg budget, not scheduling pathologies. With named
// kf pairs (consumed immediately), stream-0 exp2+repack sequenced BEFORE
// stream-1 (retires sv0 early), and the (256,3) budget, the merge fits:
// each K fragment read ONCE feeds both streams' QK MFMAs. LDS reads:
// 24 -> 16 b128/wave-iter on the dominant LDS pipe.
// Tripwires: VGPR_Count must RISE (~100+); WRITE_SIZE must stay ~24.5MB.
__global__ __launch_bounds__(256, 3) void attn_mba(
    const bf16* __restrict__ Q, const bf16* __restrict__ Kx, const bf16* __restrict__ Vtx,
    const bf16* __restrict__ Qd, const bf16* __restrict__ Kd, const bf16* __restrict__ Vtd,
    const void* w11, const void* w12, const void* w21, const void* w22,
    bf16* ctxX, bf16* ctxY, const int* flag) {
  // XCD-bijective swizzle (1536 = 8*192): each XCD gets 192 consecutive work
  // ids = 12 complete (bh) groups -> K/V L2-resident per XCD.
  const int linear = blockIdx.x + (blockIdx.y << 4);
  const int swz = (linear & 7) * 192 + (linear >> 3);
  const int qb = swz & 15;         // 0..15
  const int bh = swz >> 4;         // 0..95
  const int b = bh / 12;
  const int f = *flag;

  const float wgtX[2] = {rdscalar(w11, f), rdscalar(w12, f)};
  const float wgtY[2] = {rdscalar(w22, f), rdscalar(w21, f)};

  const size_t tok0 = (size_t)b * 1024;
  const size_t vbase = (size_t)bh * 65536;   // [bh][64][1024]
  const int fcol = (bh - b * 12) * 64;
  const int q0 = qb * 64;

  __shared__ __attribute__((aligned(16))) bf16 smem[16384];  // 32 KB
  bf16* Ks = smem;              // 2 x 4096: permuted keys x d (swizzled)
  bf16* Vs = smem + 8192;       // 2 x 4096: d x keys (swizzled)

  const int t = threadIdx.x, lane = t & 63, w = t >> 6;
  const int l15 = lane & 15, l4 = lane >> 4;

  // hoisted staging addresses (per-thread invariants; per-call adds kt only)
  const int g0 = t >> 3, slot0 = t & 7;
  const int g1 = g0 + 32;
  const int gs = (slot0 ^ (g0 & 7)) << 3;          // g1&7 == g0&7
  const int kp0 = (g0 & 32) + ((g0 & 12) << 1) + ((g0 & 16) >> 2) + (g0 & 3);
  const int kp1 = (g1 & 32) + ((g1 & 12) << 1) + ((g1 & 16) >> 2) + (g1 & 3);
  const size_t koffg0 = (tok0 + kp0) * HD + fcol + gs;
  const size_t koffg1 = (tok0 + kp1) * HD + fcol + gs;
  const size_t voffg0 = vbase + (size_t)g0 * 1024 + gs;
  const size_t voffg1 = vbase + (size_t)g1 * 1024 + gs;

  auto stage = [&](int nit) {
    const bf16* Kc = nit < 16 ? Kx : Kd;
    const bf16* Vc = nit < 16 ? Vtx : Vtd;
    const int kt64 = (nit & 15) * 64;
    bf16* Kb = Ks + (nit & 1) * 4096;
    bf16* Vb = Vs + (nit & 1) * 4096;
    gld_lds16(Kc + koffg0 + (size_t)kt64 * HD, Kb + t * 8);
    gld_lds16(Kc + koffg1 + (size_t)kt64 * HD, Kb + (t + 256) * 8);
    gld_lds16(Vc + voffg0 + kt64, Vb + t * 8);
    gld_lds16(Vc + voffg1 + kt64, Vb + (t + 256) * 8);
  };

  stage(0);

  // Q fragments direct from global (staging swizzle cancels for Q).
  const int qrow = w * 16 + l15;
  const bf16* qp0 = Q  + (tok0 + q0 + qrow) * HD + fcol;
  const bf16* qp1 = Qd + (tok0 + q0 + qrow) * HD + fcol;
  bf16x8 qf[2][2];
  qf[0][0] = *(const bf16x8*)(qp0 + (l4 << 3));
  qf[0][1] = *(const bf16x8*)(qp0 + ((4 + l4) << 3));
  qf[1][0] = *(const bf16x8*)(qp1 + (l4 << 3));
  qf[1][1] = *(const bf16x8*)(qp1 + ((4 + l4) << 3));

  // K/V fragment base: (mi*16+l15)&7 == l15&7, so the swizzle slot is
  // mi-independent; subtile mi at base + mi*1024, second half at ^32.
  const int kbase = l15 * 64 + ((l4 ^ (l15 & 7)) << 3);

  __syncthreads();   // first K/V staged

  f32x4 mixX[4] = {}, mixY[4] = {};
  f32x4 oacc[2][4] = {};
  f32x4 lsum[2] = {};          // per-lane partial row-sums

  for (int it = 0; it < 32; ++it) {
    if (it) __syncthreads();        // stage(it) landed; prev readers done
    if (it + 1 < 32) stage(it + 1); // prefetch flies across this compute
    const bf16* Kb = Ks + (it & 1) * 4096;
    const bf16* Vb = Vs + (it & 1) * 4096;

    // hoisted V fragment reads — 8 NAMED registers (stream-invariant; both
    // PVs consume them). (kbase+mi*1024)^32 == (kbase^32)+mi*1024.
    const bf16* vpa = Vb + kbase;
    const bf16* vpb = Vb + (kbase ^ 32);
    const bf16x8 va0 = *(const bf16x8*)(vpa);
    const bf16x8 va1 = *(const bf16x8*)(vpa + 1024);
    const bf16x8 va2 = *(const bf16x8*)(vpa + 2048);
    const bf16x8 va3 = *(const bf16x8*)(vpa + 3072);
    const bf16x8 vb0 = *(const bf16x8*)(vpb);
    const bf16x8 vb1 = *(const bf16x8*)(vpb + 1024);
    const bf16x8 vb2 = *(const bf16x8*)(vpb + 2048);
    const bf16x8 vb3 = *(const bf16x8*)(vpb + 3072);

    // ---- QK merged: each K fragment read ONCE, feeds both streams ----
    f32x4 sv0[4], sv1[4];
    __builtin_amdgcn_s_setprio(1);
#pragma unroll
    for (int mi = 0; mi < 4; ++mi) {
      const bf16x8 kf0 = *(const bf16x8*)(Kb + (kbase + mi * 1024));
      const bf16x8 kf1 = *(const bf16x8*)(Kb + ((kbase ^ 32) + mi * 1024));
      f32x4 a = {}, c = {};
      a = __builtin_amdgcn_mfma_f32_16x16x32_bf16(kf0, qf[0][0], a, 0, 0, 0);
      c = __builtin_amdgcn_mfma_f32_16x16x32_bf16(kf0, qf[1][0], c, 0, 0, 0);
      a = __builtin_amdgcn_mfma_f32_16x16x32_bf16(kf1, qf[0][1], a, 0, 0, 0);
      c = __builtin_amdgcn_mfma_f32_16x16x32_bf16(kf1, qf[1][1], c, 0, 0, 0);
      sv0[mi] = a; sv1[mi] = c;
    }
    __builtin_amdgcn_s_setprio(0);

    // stream-0 exp2 + repack FIRST (retires sv0 before sv1's exp2 -> lower
    // simultaneous register liveness)
    bf16x8 pf00, pf01;
    {
      f32x4 ls = lsum[0];
#pragma unroll
      for (int mi = 0; mi < 4; ++mi) {
        f32x4 e;
#pragma unroll
        for (int r = 0; r < 4; ++r) e[r] = exp2fast(sv0[mi][r]);
        sv0[mi] = e;
        ls += e;
      }
      lsum[0] = ls;
#pragma unroll
      for (int j = 0; j < 8; ++j) {
        pf00[j] = (bf16)sv0[(j >> 2)][j & 3];
        pf01[j] = (bf16)sv0[2 + (j >> 2)][j & 3];
      }
    }
    bf16x8 pf10, pf11;
    {
      f32x4 ls = lsum[1];
#pragma unroll
      for (int mi = 0; mi < 4; ++mi) {
        f32x4 e;
#pragma unroll
        for (int r = 0; r < 4; ++r) e[r] = exp2fast(sv1[mi][r]);
        sv1[mi] = e;
        ls += e;
      }
      lsum[1] = ls;
#pragma unroll
      for (int j = 0; j < 8; ++j) {
        pf10[j] = (bf16)sv1[(j >> 2)][j & 3];
        pf11[j] = (bf16)sv1[2 + (j >> 2)][j & 3];
      }
    }

    // ---- PV: 8 shared V regs feed both streams' accumulators ----
    __builtin_amdgcn_s_setprio(1);
    oacc[0][0] = __builtin_amdgcn_mfma_f32_16x16x32_bf16(va0, pf00, oacc[0][0], 0, 0, 0);
    oacc[1][0] = __builtin_amdgcn_mfma_f32_16x16x32_bf16(va0, pf10, oacc[1][0], 0, 0, 0);
    oacc[0][1] = __builtin_amdgcn_mfma_f32_16x16x32_bf16(va1, pf00, oacc[0][1], 0, 0, 0);
    oacc[1][1] = __builtin_amdgcn_mfma_f32_16x16x32_bf16(va1, pf10, oacc[1][1], 0, 0, 0);
    oacc[0][2] = __builtin_amdgcn_mfma_f32_16x16x32_bf16(va2, pf00, oacc[0][2], 0, 0, 0);
    oacc[1][2] = __builtin_amdgcn_mfma_f32_16x16x32_bf16(va2, pf10, oacc[1][2], 0, 0, 0);
    oacc[0][3] = __builtin_amdgcn_mfma_f32_16x16x32_bf16(va3, pf00, oacc[0][3], 0, 0, 0);
    oacc[1][3] = __builtin_amdgcn_mfma_f32_16x16x32_bf16(va3, pf10, oacc[1][3], 0, 0, 0);
    oacc[0][0] = __builtin_amdgcn_mfma_f32_16x16x32_bf16(vb0, pf01, oacc[0][0], 0, 0, 0);
    oacc[1][0] = __builtin_amdgcn_mfma_f32_16x16x32_bf16(vb0, pf11, oacc[1][0], 0, 0, 0);
    oacc[0][1] = __builtin_amdgcn_mfma_f32_16x16x32_bf16(vb1, pf01, oacc[0][1], 0, 0, 0);
    oacc[1][1] = __builtin_amdgcn_mfma_f32_16x16x32_bf16(vb1, pf11, oacc[1][1], 0, 0, 0);
    oacc[0][2] = __builtin_amdgcn_mfma_f32_16x16x32_bf16(vb2, pf01, oacc[0][2], 0, 0, 0);
    oacc[1][2] = __builtin_amdgcn_mfma_f32_16x16x32_bf16(vb2, pf11, oacc[1][2], 0, 0, 0);
    oacc[0][3] = __builtin_amdgcn_mfma_f32_16x16x32_bf16(vb3, pf01, oacc[0][3], 0, 0, 0);
    oacc[1][3] = __builtin_amdgcn_mfma_f32_16x16x32_bf16(vb3, pf11, oacc[1][3], 0, 0, 0);
    __builtin_amdgcn_s_setprio(0);

    if ((it & 15) == 15) {   // phase finalize: the ONLY cross-lane reduction
      const int ph = it >> 4;
      float l0 = (lsum[0][0] + lsum[0][1]) + (lsum[0][2] + lsum[0][3]);
      float l1 = (lsum[1][0] + lsum[1][1]) + (lsum[1][2] + lsum[1][3]);
      l0 += __shfl_xor(l0, 16); l0 += __shfl_xor(l0, 32);
      l1 += __shfl_xor(l1, 16); l1 += __shfl_xor(l1, 32);
      const float scX = wgtX[ph] / l0;
      const float scY = wgtY[ph] / l1;
#pragma unroll
      for (int mi = 0; mi < 4; ++mi) {
#pragma unroll
        for (int r = 0; r < 4; ++r) {
          mixX[mi][r] += scX * oacc[0][mi][r];
          mixY[mi][r] += scY * oacc[1][mi][r];
        }
        oacc[0][mi] = f32x4{};
        oacc[1][mi] = f32x4{};
      }
      lsum[0] = f32x4{};
      lsum[1] = f32x4{};
    }
  }

  // epilogue: transpose O^T -> O through LDS, coalesced b128 stores (both outs)
  __syncthreads();
  bf16* TX = smem;          // 64 x 72
  bf16* TY = smem + 4608;   // 64 x 72
#pragma unroll
  for (int mi = 0; mi < 4; ++mi)
#pragma unroll
    for (int r = 0; r < 4; ++r) {
      TX[qrow * 72 + mi * 16 + l4 * 4 + r] = (bf16)mixX[mi][r];
      TY[qrow * 72 + mi * 16 + l4 * 4 + r] = (bf16)mixY[mi][r];
    }
  __syncthreads();
#pragma unroll
  for (int i = 0; i < 2; ++i) {
    const int q = t + i * 256;
    const int g = q >> 3, dc = (q & 7) * 8;
    *(bf16x8*)(ctxX + (tok0 + q0 + g) * HD + fcol + dc) = *(const bf16x8*)(TX + g * 72 + dc);
    *(bf16x8*)(ctxY + (tok0 + q0 + g) * HD + fcol + dc) = *(const bf16x8*)(TY + g * 72 + dc);
  }
}

extern "C" void kernel_launch(void* const* d_in, const int* in_sizes, int n_in,
                              void* d_out, int out_size, void* d_ws, size_t ws_size,
                              hipStream_t stream) {
  (void)in_sizes; (void)n_in; (void)out_size;
  const void* x = d_in[0];
  const void* y = d_in[1];

  bf16* ws = (bf16*)d_ws;
  bf16* Qb   = ws + 0ull * ELTS;
  bf16* Kb   = ws + 1ull * ELTS;
  bf16* Vtb  = ws + 2ull * ELTS;   // [b][h][d][s]
  bf16* Qdb  = ws + 3ull * ELTS;
  bf16* Kdb  = ws + 4ull * ELTS;
  bf16* Vtdb = ws + 5ull * ELTS;
  bf16* ctxX = Qb;    // alias: safe (block-local read-then-write, disjoint slices)
  bf16* ctxY = Qdb;
  int* flag = (int*)(ws + 6ull * ELTS);

  // Projection W/bias bf16 scratch in spare workspace (survives until the proj
  // GEMM, untouched by QKV GEMM / attn). Runtime-guarded on ws_size.
  const size_t extra_elems = 6ull * ELTS + 32 + 2ull * WELTS + 2 * 768;
  const bool big_ws = ws_size >= extra_elems * sizeof(bf16);
  bf16* extraW = ws + 6ull * ELTS + 32;       // 2 x WELTS (Wo, Wod)
  bf16* extraB = extraW + 2ull * WELTS;       // 2 x 768   (bo, bod)

  // Conversion scratch in d_out — consumed ONLY by the QKV GEMM (stream-ordered
  // before any d_out write by the projection GEMM).
  bf16* cb = (bf16*)d_out;
  bf16* xb = cb;                              // ELTS
  bf16* yb = cb + (size_t)ELTS;               // ELTS
  bf16* Wcv = cb + 2ull * ELTS;               // 6 x WELTS (Wq,Wk,Wv,Wqd,Wkd,Wvd)
  bf16* bcv = Wcv + 6ull * WELTS;             // 6 x 768
  // total: 2*ELTS + 6*WELTS + 6*768 bf16 = 32.3 MB < 50.3 MB fp32 out region

  probe_dtype<<<dim3(1), dim3(64), 0, stream>>>((const unsigned int*)x, flag);

  CvtArgs ca;
  int nseg = 14;
  {
    const int wsrc[6] = {2, 4, 6, 10, 12, 14};   // QKV weights only
    ca.src[0] = (const float*)x;  ca.dst[0] = xb;  ca.n[0] = ELTS;
    ca.src[1] = (const float*)y;  ca.dst[1] = yb;  ca.n[1] = ELTS;
    for (int i = 0; i < 6; ++i) {
      ca.src[2 + i] = (const float*)d_in[wsrc[i]];
      ca.dst[2 + i] = Wcv + (size_t)i * WELTS;
      ca.n[2 + i] = WELTS;
      ca.src[8 + i] = (const float*)d_in[wsrc[i] + 1];
      ca.dst[8 + i] = bcv + (size_t)i * 768;
      ca.n[8 + i] = 768;
    }
    if (big_ws) {
      ca.src[14] = (const float*)d_in[8];  ca.dst[14] = extraW;         ca.n[14] = WELTS;
      ca.src[15] = (const float*)d_in[16]; ca.dst[15] = extraW + WELTS; ca.n[15] = WELTS;
      ca.src[16] = (const float*)d_in[9];  ca.dst[16] = extraB;         ca.n[16] = 768;
      ca.src[17] = (const float*)d_in[17]; ca.dst[17] = extraB + 768;   ca.n[17] = 768;
      nseg = 18;
    }
    ca.flag = flag;
  }
  convert_inputs<<<dim3(512, nseg), dim3(256), 0, stream>>>(ca);

  GemmArgs gq;
  {
    const void* A6[6]  = {x, x, x, y, y, y};
    const void* Ac6[6] = {xb, xb, xb, yb, yb, yb};
    const int di[6] = {2, 4, 6, 10, 12, 14};
    bf16* C6[6] = {Qb, Kb, Vtb, Qdb, Kdb, Vtdb};
    for (int i = 0; i < 6; ++i) {
      gq.A[i] = A6[i]; gq.Ac[i] = Ac6[i];
      gq.W[i] = d_in[di[i]]; gq.Wc[i] = Wcv + (size_t)i * WELTS;
      gq.bias[i] = d_in[di[i] + 1]; gq.biasc[i] = bcv + (size_t)i * 768;
      gq.s0[i] = nullptr; gq.s1[i] = nullptr; gq.C[i] = C6[i];
      // Q, Qd pre-scaled by 1/sqrt(64) * log2(e) -> softmax in exp2 domain
      gq.cmul[i] = (i == 0 || i == 3) ? 0.18033688011112042f : 1.0f;
      gq.c_fixed[i] = 1; gq.ext_w[i] = 0; gq.out_elem_off[i] = 0;
      gq.vt[i] = (i == 2 || i == 5) ? 1 : 0;
    }
    gq.flag = flag;
  }
  gemm_bt<<<dim3(64, 6, 6), dim3(256), 0, stream>>>(gq);

  attn_mba<<<dim3(16, 96), dim3(256), 0, stream>>>(
      Qb, Kb, Vtb, Qdb, Kdb, Vtdb, d_in[18], d_in[19], d_in[20], d_in[21],
      ctxX, ctxY, flag);

  GemmArgs gp;
  for (int i = 0; i < 6; ++i) {
    gp.A[i] = ctxX; gp.Ac[i] = ctxX;
    gp.W[i] = d_in[8]; gp.Wc[i] = d_in[8];        // fp32 original when flag==0
    gp.bias[i] = d_in[9]; gp.biasc[i] = d_in[9];  // fp32 original when flag==0
    gp.s0[i] = d_in[18]; gp.s1[i] = d_in[19]; gp.C[i] = d_out;
    gp.cmul[i] = 1.0f; gp.c_fixed[i] = 0; gp.vt[i] = 0;
    gp.ext_w[i] = 1; gp.out_elem_off[i] = 0;
  }
  gp.A[1] = ctxY; gp.Ac[1] = ctxY;
  gp.W[1] = d_in[16]; gp.Wc[1] = d_in[16];
  gp.bias[1] = d_in[17]; gp.biasc[1] = d_in[17];
  gp.s0[1] = d_in[20]; gp.s1[1] = d_in[21];
  gp.out_elem_off[1] = (long long)ELTS;
  if (big_ws) {   // pre-converted bf16 projection weights/biases
    gp.Wc[0] = extraW;         gp.biasc[0] = extraB;       gp.ext_w[0] = 0;
    gp.Wc[1] = extraW + WELTS; gp.biasc[1] = extraB + 768; gp.ext_w[1] = 0;
  }
  gp.flag = flag;
  gemm_bt<<<dim3(64, 6, 2), dim3(256), 0, stream>>>(gp);
}

// Round 12
// 371.960 us; speedup vs baseline: 1.0564x; 1.0564x over previous
//
#include <hip/hip_runtime.h>

typedef __bf16 bf16;
typedef __bf16 bf16x8 __attribute__((ext_vector_type(8)));
typedef float f32x4 __attribute__((ext_vector_type(4)));

#define HD 768
#define ELTS 6291456   // 8*1024*768
#define WELTS 589824   // 768*768

__device__ __forceinline__ void gld_lds16(const bf16* g, bf16* l) {
  __builtin_amdgcn_global_load_lds((const __attribute__((address_space(1))) void*)g,
                                   (__attribute__((address_space(3))) void*)l, 16, 0, 0);
}

__device__ __forceinline__ float rdscalar(const void* p, int f) {
  return f ? (float)((const bf16*)p)[0] : ((const float*)p)[0];
}

__device__ __forceinline__ float exp2fast(float x) {
#if __has_builtin(__builtin_amdgcn_exp2f)
  return __builtin_amdgcn_exp2f(x);
#else
  return __builtin_exp2f(x);
#endif
}

__global__ void probe_dtype(const unsigned int* __restrict__ x, int* flag) {
  const int t = threadIdx.x;  // 64 threads
  int bad = 0;
#pragma unroll
  for (int i = 0; i < 4; ++i) {
    unsigned int wd = x[t * 4 + i];
    unsigned int e0 = (wd >> 7) & 0xFF;
    unsigned int e1 = (wd >> 23) & 0xFF;
    bad += (e0 >= 134) + (e1 >= 134);
  }
  unsigned long long m = __ballot(bad > 0);
  if (t == 0) *flag = (m == 0ULL) ? 1 : 0;   // 1 = bf16 inputs
}

// fp32 -> bf16 conversion (flag==0 only). QKV-side destinations live in d_out
// (consumed ONLY by the QKV GEMM, stream-ordered before the projection GEMM
// writes d_out). Projection W/bias destinations live in spare workspace when
// ws_size permits.
struct CvtArgs {
  const float* src[20];
  bf16* dst[20];
  int n[20];
  const int* flag;
};
__global__ __launch_bounds__(256) void convert_inputs(CvtArgs a) {
  if (*a.flag) return;
  const int seg = blockIdx.y;
  const float* s = a.src[seg];
  bf16* d = a.dst[seg];
  const int n4 = a.n[seg] >> 2;
  for (int i = blockIdx.x * blockDim.x + threadIdx.x; i < n4; i += gridDim.x * blockDim.x) {
    f32x4 v = *(const f32x4*)(s + i * 4);
    bf16 o[4];
#pragma unroll
    for (int e = 0; e < 4; ++e) o[e] = (bf16)v[e];
    *(unsigned long long*)(d + i * 4) = *(unsigned long long*)o;
  }
}

struct GemmArgs {
  const void* A[6];     // bf16 when flag==1
  const void* Ac[6];    // bf16 when flag==0 (converted / internal)
  const void* W[6];     // bf16 when flag==1
  const void* Wc[6];    // flag==0: bf16 converted (ext_w=0) or fp32 original (ext_w=1)
  const void* bias[6];  // bf16 when flag==1
  const void* biasc[6]; // flag==0: bf16 converted (ext_w=0) or fp32 original (ext_w=1)
  const void* s0[6];
  const void* s1[6];
  void* C[6];
  float cmul[6];        // epilogue scale on (acc + bias)
  int c_fixed[6];       // 1: C always internal bf16; 0: C dtype follows flag
  int vt[6];            // 1: write C transposed per-head: [b][h][d=64][s=1024]
  int ext_w[6];         // 1: when flag==0, W/bias are fp32 -> convert in-kernel
  long long out_elem_off[6];
  const int* flag;
};

// C[M=8192, N=768] = (A[M,768] @ W[N,768]^T + bias*bscale) * cmul
// BK=64 k-steps, XOR-swizzled LDS staging (conflict-free fragment reads).
__global__ __launch_bounds__(256) void gemm_bt(GemmArgs args) {
  const int g = blockIdx.z;
  const int f = *args.flag;
  const bool c_bf = args.c_fixed[g] || f;
  const bool w_f32 = (!f) && args.ext_w[g];
  const bf16* __restrict__ A = (const bf16*)(f ? args.A[g] : args.Ac[g]);
  const void* __restrict__ Wp = f ? args.W[g] : args.Wc[g];
  const void* __restrict__ bias = f ? args.bias[g] : args.biasc[g];
  bf16* Cb = (bf16*)args.C[g] + args.out_elem_off[g];
  float* Cf = (float*)args.C[g] + args.out_elem_off[g];
  float bscale = 1.0f;
  if (args.s0[g]) bscale = rdscalar(args.s0[g], f) + rdscalar(args.s1[g], f);
  const float cmul = args.cmul[g];

  const int m0 = blockIdx.x * 128;
  const int n0 = blockIdx.y * 128;
  const int t = threadIdx.x;
  const int lane = t & 63;
  const int w = t >> 6;
  const int wm = (w >> 1) * 64, wn = (w & 1) * 64;

  __shared__ __attribute__((aligned(16))) bf16 As[128 * 64];
  __shared__ __attribute__((aligned(16))) bf16 Bs[128 * 64];

  f32x4 acc[4][4] = {};

  // staging map: chunk q = t + i*256 -> row = q>>3 (row&7 invariant over i),
  // slot = q&7; global col group = slot ^ (row&7); LDS dest linear.
  const int row_s = t >> 3, slot_s = t & 7;
  const int gswz = (slot_s ^ (row_s & 7)) << 3;

  const int fr = lane & 15;
  const int l4 = lane >> 4;
  // fragment read slots for the two K=32 subtiles
  const int sR0 = ((l4) ^ (fr & 7)) << 3;
  const int sR1 = ((4 + l4) ^ (fr & 7)) << 3;

  for (int kb = 0; kb < 12; ++kb) {
    const int k0 = kb * 64;
#pragma unroll
    for (int i = 0; i < 4; ++i) {
      const int row = row_s + i * 32;
      gld_lds16(A + (size_t)(m0 + row) * HD + k0 + gswz, As + (t + i * 256) * 8);
    }
    if (!w_f32) {
#pragma unroll
      for (int i = 0; i < 4; ++i) {
        const int row = row_s + i * 32;
        gld_lds16((const bf16*)Wp + (size_t)(n0 + row) * HD + k0 + gswz, Bs + (t + i * 256) * 8);
      }
    } else {
      const float* Wf = (const float*)Wp;
#pragma unroll
      for (int i = 0; i < 4; ++i) {
        const int row = row_s + i * 32;
        const size_t src = (size_t)(n0 + row) * HD + k0 + gswz;
        f32x4 u0 = *(const f32x4*)(Wf + src), u1 = *(const f32x4*)(Wf + src + 4);
        bf16x8 v;
#pragma unroll
        for (int e = 0; e < 4; ++e) { v[e] = (bf16)u0[e]; v[e + 4] = (bf16)u1[e]; }
        *(bf16x8*)(Bs + (t + i * 256) * 8) = v;
      }
    }
    __syncthreads();
#pragma unroll
    for (int kk = 0; kk < 2; ++kk) {
      const int sR = kk ? sR1 : sR0;
      bf16x8 af[4], bfr[4];
#pragma unroll
      for (int mi = 0; mi < 4; ++mi)
        af[mi] = *(const bf16x8*)(As + (wm + mi * 16 + fr) * 64 + sR);
#pragma unroll
      for (int ni = 0; ni < 4; ++ni)
        bfr[ni] = *(const bf16x8*)(Bs + (wn + ni * 16 + fr) * 64 + sR);
#pragma unroll
      for (int mi = 0; mi < 4; ++mi)
#pragma unroll
        for (int ni = 0; ni < 4; ++ni)
          acc[mi][ni] = __builtin_amdgcn_mfma_f32_16x16x32_bf16(af[mi], bfr[ni], acc[mi][ni], 0, 0, 0);
    }
    __syncthreads();
  }

  const int rq = (lane >> 4) * 4;
  const int is_vt = args.vt[g];
#pragma unroll
  for (int ni = 0; ni < 4; ++ni) {
    const int col = n0 + wn + ni * 16 + fr;
    const float bv = (w_f32 ? ((const float*)bias)[col]
                            : (float)((const bf16*)bias)[col]) * bscale;
#pragma unroll
    for (int mi = 0; mi < 4; ++mi) {
      const int row = m0 + wm + mi * 16 + rq;   // row % 4 == 0
      if (is_vt) {
        // 4 consecutive tokens (same bb, same d) -> one 8B store
        const int bb = row >> 10, s = row & 1023;
        const int hh = col >> 6, d = col & 63;
        bf16 tmp[4];
#pragma unroll
        for (int r = 0; r < 4; ++r) tmp[r] = (bf16)((acc[mi][ni][r] + bv) * cmul);
        *(unsigned long long*)(Cb + (((size_t)(bb * 12 + hh)) << 16) + (d << 10) + s) =
            *(const unsigned long long*)tmp;
      } else {
#pragma unroll
        for (int r = 0; r < 4; ++r) {
          const float val = (acc[mi][ni][r] + bv) * cmul;
          if (c_bf) Cb[(size_t)(row + r) * HD + col] = (bf16)val;
          else      Cf[(size_t)(row + r) * HD + col] = val;
        }
      }
    }
  }
}

// FUSED two-stream flash attention, SHIFT-FREE softmax — K-merge A/B round 3:
// IDENTICAL source to R11 except __launch_bounds__(256,2).
// Mechanism discovered in R11: rocprof VGPR_Count EXCLUDES the AGPR half of
// the unified file. R9's true footprint is 84 VGPR + 64 AGPR (oacc+mix)
// ~ 148 of the (256,3)~170 budget. The K-merge needs +32 live regs -> 180 >
// 170 -> allocator held 84 and spilled (WRITE_SIZE 24.5->49.7MB, dur 141us).
// (256,2) raises the budget to 256; liveness ~180 fits with slack. Occupancy
// cost is tiny: measured occupancy was already ~2.2 blocks/CU; cap is 2.
// Tripwires: VGPR_Count MUST rise (~110-140); WRITE_SIZE back to ~24.6MB.
// If attn >= 120us anyway -> revert to R9 attn permanently next round.
__global__ __launch_bounds__(256, 2) void attn_mba(
    const bf16* __restrict__ Q, const bf16* __restrict__ Kx, const bf16* __restrict__ Vtx,
    const bf16* __restrict__ Qd, const bf16* __restrict__ Kd, const bf16* __restrict__ Vtd,
    const void* w11, const void* w12, const void* w21, const void* w22,
    bf16* ctxX, bf16* ctxY, const int* flag) {
  // XCD-bijective swizzle (1536 = 8*192): each XCD gets 192 consecutive work
  // ids = 12 complete (bh) groups -> K/V L2-resident per XCD.
  const int linear = blockIdx.x + (blockIdx.y << 4);
  const int swz = (linear & 7) * 192 + (linear >> 3);
  const int qb = swz & 15;         // 0..15
  const int bh = swz >> 4;         // 0..95
  const int b = bh / 12;
  const int f = *flag;

  const float wgtX[2] = {rdscalar(w11, f), rdscalar(w12, f)};
  const float wgtY[2] = {rdscalar(w22, f), rdscalar(w21, f)};

  const size_t tok0 = (size_t)b * 1024;
  const size_t vbase = (size_t)bh * 65536;   // [bh][64][1024]
  const int fcol = (bh - b * 12) * 64;
  const int q0 = qb * 64;

  __shared__ __attribute__((aligned(16))) bf16 smem[16384];  // 32 KB
  bf16* Ks = smem;              // 2 x 4096: permuted keys x d (swizzled)
  bf16* Vs = smem + 8192;       // 2 x 4096: d x keys (swizzled)

  const int t = threadIdx.x, lane = t & 63, w = t >> 6;
  const int l15 = lane & 15, l4 = lane >> 4;

  // hoisted staging addresses (per-thread invariants; per-call adds kt only)
  const int g0 = t >> 3, slot0 = t & 7;
  const int g1 = g0 + 32;
  const int gs = (slot0 ^ (g0 & 7)) << 3;          // g1&7 == g0&7
  const int kp0 = (g0 & 32) + ((g0 & 12) << 1) + ((g0 & 16) >> 2) + (g0 & 3);
  const int kp1 = (g1 & 32) + ((g1 & 12) << 1) + ((g1 & 16) >> 2) + (g1 & 3);
  const size_t koffg0 = (tok0 + kp0) * HD + fcol + gs;
  const size_t koffg1 = (tok0 + kp1) * HD + fcol + gs;
  const size_t voffg0 = vbase + (size_t)g0 * 1024 + gs;
  const size_t voffg1 = vbase + (size_t)g1 * 1024 + gs;

  auto stage = [&](int nit) {
    const bf16* Kc = nit < 16 ? Kx : Kd;
    const bf16* Vc = nit < 16 ? Vtx : Vtd;
    const int kt64 = (nit & 15) * 64;
    bf16* Kb = Ks + (nit & 1) * 4096;
    bf16* Vb = Vs + (nit & 1) * 4096;
    gld_lds16(Kc + koffg0 + (size_t)kt64 * HD, Kb + t * 8);
    gld_lds16(Kc + koffg1 + (size_t)kt64 * HD, Kb + (t + 256) * 8);
    gld_lds16(Vc + voffg0 + kt64, Vb + t * 8);
    gld_lds16(Vc + voffg1 + kt64, Vb + (t + 256) * 8);
  };

  stage(0);

  // Q fragments direct from global (staging swizzle cancels for Q).
  const int qrow = w * 16 + l15;
  const bf16* qp0 = Q  + (tok0 + q0 + qrow) * HD + fcol;
  const bf16* qp1 = Qd + (tok0 + q0 + qrow) * HD + fcol;
  bf16x8 qf[2][2];
  qf[0][0] = *(const bf16x8*)(qp0 + (l4 << 3));
  qf[0][1] = *(const bf16x8*)(qp0 + ((4 + l4) << 3));
  qf[1][0] = *(const bf16x8*)(qp1 + (l4 << 3));
  qf[1][1] = *(const bf16x8*)(qp1 + ((4 + l4) << 3));

  // K/V fragment base: (mi*16+l15)&7 == l15&7, so the swizzle slot is
  // mi-independent; subtile mi at base + mi*1024, second half at ^32.
  const int kbase = l15 * 64 + ((l4 ^ (l15 & 7)) << 3);

  __syncthreads();   // first K/V staged

  f32x4 mixX[4] = {}, mixY[4] = {};
  f32x4 oacc[2][4] = {};
  f32x4 lsum[2] = {};          // per-lane partial row-sums

  for (int it = 0; it < 32; ++it) {
    if (it) __syncthreads();        // stage(it) landed; prev readers done
    if (it + 1 < 32) stage(it + 1); // prefetch flies across this compute
    const bf16* Kb = Ks + (it & 1) * 4096;
    const bf16* Vb = Vs + (it & 1) * 4096;

    // hoisted V fragment reads — 8 NAMED registers (stream-invariant; both
    // PVs consume them). (kbase+mi*1024)^32 == (kbase^32)+mi*1024.
    const bf16* vpa = Vb + kbase;
    const bf16* vpb = Vb + (kbase ^ 32);
    const bf16x8 va0 = *(const bf16x8*)(vpa);
    const bf16x8 va1 = *(const bf16x8*)(vpa + 1024);
    const bf16x8 va2 = *(const bf16x8*)(vpa + 2048);
    const bf16x8 va3 = *(const bf16x8*)(vpa + 3072);
    const bf16x8 vb0 = *(const bf16x8*)(vpb);
    const bf16x8 vb1 = *(const bf16x8*)(vpb + 1024);
    const bf16x8 vb2 = *(const bf16x8*)(vpb + 2048);
    const bf16x8 vb3 = *(const bf16x8*)(vpb + 3072);

    // ---- QK merged: each K fragment read ONCE, feeds both streams ----
    f32x4 sv0[4], sv1[4];
    __builtin_amdgcn_s_setprio(1);
#pragma unroll
    for (int mi = 0; mi < 4; ++mi) {
      const bf16x8 kf0 = *(const bf16x8*)(Kb + (kbase + mi * 1024));
      const bf16x8 kf1 = *(const bf16x8*)(Kb + ((kbase ^ 32) + mi * 1024));
      f32x4 a = {}, c = {};
      a = __builtin_amdgcn_mfma_f32_16x16x32_bf16(kf0, qf[0][0], a, 0, 0, 0);
      c = __builtin_amdgcn_mfma_f32_16x16x32_bf16(kf0, qf[1][0], c, 0, 0, 0);
      a = __builtin_amdgcn_mfma_f32_16x16x32_bf16(kf1, qf[0][1], a, 0, 0, 0);
      c = __builtin_amdgcn_mfma_f32_16x16x32_bf16(kf1, qf[1][1], c, 0, 0, 0);
      sv0[mi] = a; sv1[mi] = c;
    }
    __builtin_amdgcn_s_setprio(0);

    // stream-0 exp2 + repack FIRST (retires sv0 before sv1's exp2 -> lower
    // simultaneous register liveness)
    bf16x8 pf00, pf01;
    {
      f32x4 ls = lsum[0];
#pragma unroll
      for (int mi = 0; mi < 4; ++mi) {
        f32x4 e;
#pragma unroll
        for (int r = 0; r < 4; ++r) e[r] = exp2fast(sv0[mi][r]);
        sv0[mi] = e;
        ls += e;
      }
      lsum[0] = ls;
#pragma unroll
      for (int j = 0; j < 8; ++j) {
        pf00[j] = (bf16)sv0[(j >> 2)][j & 3];
        pf01[j] = (bf16)sv0[2 + (j >> 2)][j & 3];
      }
    }
    bf16x8 pf10, pf11;
    {
      f32x4 ls = lsum[1];
#pragma unroll
      for (int mi = 0; mi < 4; ++mi) {
        f32x4 e;
#pragma unroll
        for (int r = 0; r < 4; ++r) e[r] = exp2fast(sv1[mi][r]);
        sv1[mi] = e;
        ls += e;
      }
      lsum[1] = ls;
#pragma unroll
      for (int j = 0; j < 8; ++j) {
        pf10[j] = (bf16)sv1[(j >> 2)][j & 3];
        pf11[j] = (bf16)sv1[2 + (j >> 2)][j & 3];
      }
    }

    // ---- PV: 8 shared V regs feed both streams' accumulators ----
    __builtin_amdgcn_s_setprio(1);
    oacc[0][0] = __builtin_amdgcn_mfma_f32_16x16x32_bf16(va0, pf00, oacc[0][0], 0, 0, 0);
    oacc[1][0] = __builtin_amdgcn_mfma_f32_16x16x32_bf16(va0, pf10, oacc[1][0], 0, 0, 0);
    oacc[0][1] = __builtin_amdgcn_mfma_f32_16x16x32_bf16(va1, pf00, oacc[0][1], 0, 0, 0);
    oacc[1][1] = __builtin_amdgcn_mfma_f32_16x16x32_bf16(va1, pf10, oacc[1][1], 0, 0, 0);
    oacc[0][2] = __builtin_amdgcn_mfma_f32_16x16x32_bf16(va2, pf00, oacc[0][2], 0, 0, 0);
    oacc[1][2] = __builtin_amdgcn_mfma_f32_16x16x32_bf16(va2, pf10, oacc[1][2], 0, 0, 0);
    oacc[0][3] = __builtin_amdgcn_mfma_f32_16x16x32_bf16(va3, pf00, oacc[0][3], 0, 0, 0);
    oacc[1][3] = __builtin_amdgcn_mfma_f32_16x16x32_bf16(va3, pf10, oacc[1][3], 0, 0, 0);
    oacc[0][0] = __builtin_amdgcn_mfma_f32_16x16x32_bf16(vb0, pf01, oacc[0][0], 0, 0, 0);
    oacc[1][0] = __builtin_amdgcn_mfma_f32_16x16x32_bf16(vb0, pf11, oacc[1][0], 0, 0, 0);
    oacc[0][1] = __builtin_amdgcn_mfma_f32_16x16x32_bf16(vb1, pf01, oacc[0][1], 0, 0, 0);
    oacc[1][1] = __builtin_amdgcn_mfma_f32_16x16x32_bf16(vb1, pf11, oacc[1][1], 0, 0, 0);
    oacc[0][2] = __builtin_amdgcn_mfma_f32_16x16x32_bf16(vb2, pf01, oacc[0][2], 0, 0, 0);
    oacc[1][2] = __builtin_amdgcn_mfma_f32_16x16x32_bf16(vb2, pf11, oacc[1][2], 0, 0, 0);
    oacc[0][3] = __builtin_amdgcn_mfma_f32_16x16x32_bf16(vb3, pf01, oacc[0][3], 0, 0, 0);
    oacc[1][3] = __builtin_amdgcn_mfma_f32_16x16x32_bf16(vb3, pf11, oacc[1][3], 0, 0, 0);
    __builtin_amdgcn_s_setprio(0);

    if ((it & 15) == 15) {   // phase finalize: the ONLY cross-lane reduction
      const int ph = it >> 4;
      float l0 = (lsum[0][0] + lsum[0][1]) + (lsum[0][2] + lsum[0][3]);
      float l1 = (lsum[1][0] + lsum[1][1]) + (lsum[1][2] + lsum[1][3]);
      l0 += __shfl_xor(l0, 16); l0 += __shfl_xor(l0, 32);
      l1 += __shfl_xor(l1, 16); l1 += __shfl_xor(l1, 32);
      const float scX = wgtX[ph] / l0;
      const float scY = wgtY[ph] / l1;
#pragma unroll
      for (int mi = 0; mi < 4; ++mi) {
#pragma unroll
        for (int r = 0; r < 4; ++r) {
          mixX[mi][r] += scX * oacc[0][mi][r];
          mixY[mi][r] += scY * oacc[1][mi][r];
        }
        oacc[0][mi] = f32x4{};
        oacc[1][mi] = f32x4{};
      }
      lsum[0] = f32x4{};
      lsum[1] = f32x4{};
    }
  }

  // epilogue: transpose O^T -> O through LDS, coalesced b128 stores (both outs)
  __syncthreads();
  bf16* TX = smem;          // 64 x 72
  bf16* TY = smem + 4608;   // 64 x 72
#pragma unroll
  for (int mi = 0; mi < 4; ++mi)
#pragma unroll
    for (int r = 0; r < 4; ++r) {
      TX[qrow * 72 + mi * 16 + l4 * 4 + r] = (bf16)mixX[mi][r];
      TY[qrow * 72 + mi * 16 + l4 * 4 + r] = (bf16)mixY[mi][r];
    }
  __syncthreads();
#pragma unroll
  for (int i = 0; i < 2; ++i) {
    const int q = t + i * 256;
    const int g = q >> 3, dc = (q & 7) * 8;
    *(bf16x8*)(ctxX + (tok0 + q0 + g) * HD + fcol + dc) = *(const bf16x8*)(TX + g * 72 + dc);
    *(bf16x8*)(ctxY + (tok0 + q0 + g) * HD + fcol + dc) = *(const bf16x8*)(TY + g * 72 + dc);
  }
}

extern "C" void kernel_launch(void* const* d_in, const int* in_sizes, int n_in,
                              void* d_out, int out_size, void* d_ws, size_t ws_size,
                              hipStream_t stream) {
  (void)in_sizes; (void)n_in; (void)out_size;
  const void* x = d_in[0];
  const void* y = d_in[1];

  bf16* ws = (bf16*)d_ws;
  bf16* Qb   = ws + 0ull * ELTS;
  bf16* Kb   = ws + 1ull * ELTS;
  bf16* Vtb  = ws + 2ull * ELTS;   // [b][h][d][s]
  bf16* Qdb  = ws + 3ull * ELTS;
  bf16* Kdb  = ws + 4ull * ELTS;
  bf16* Vtdb = ws + 5ull * ELTS;
  bf16* ctxX = Qb;    // alias: safe (block-local read-then-write, disjoint slices)
  bf16* ctxY = Qdb;
  int* flag = (int*)(ws + 6ull * ELTS);

  // Projection W/bias bf16 scratch in spare workspace (survives until the proj
  // GEMM, untouched by QKV GEMM / attn). Runtime-guarded on ws_size.
  const size_t extra_elems = 6ull * ELTS + 32 + 2ull * WELTS + 2 * 768;
  const bool big_ws = ws_size >= extra_elems * sizeof(bf16);
  bf16* extraW = ws + 6ull * ELTS + 32;       // 2 x WELTS (Wo, Wod)
  bf16* extraB = extraW + 2ull * WELTS;       // 2 x 768   (bo, bod)

  // Conversion scratch in d_out — consumed ONLY by the QKV GEMM (stream-ordered
  // before any d_out write by the projection GEMM).
  bf16* cb = (bf16*)d_out;
  bf16* xb = cb;                              // ELTS
  bf16* yb = cb + (size_t)ELTS;               // ELTS
  bf16* Wcv = cb + 2ull * ELTS;               // 6 x WELTS (Wq,Wk,Wv,Wqd,Wkd,Wvd)
  bf16* bcv = Wcv + 6ull * WELTS;             // 6 x 768
  // total: 2*ELTS + 6*WELTS + 6*768 bf16 = 32.3 MB < 50.3 MB fp32 out region

  probe_dtype<<<dim3(1), dim3(64), 0, stream>>>((const unsigned int*)x, flag);

  CvtArgs ca;
  int nseg = 14;
  {
    const int wsrc[6] = {2, 4, 6, 10, 12, 14};   // QKV weights only
    ca.src[0] = (const float*)x;  ca.dst[0] = xb;  ca.n[0] = ELTS;
    ca.src[1] = (const float*)y;  ca.dst[1] = yb;  ca.n[1] = ELTS;
    for (int i = 0; i < 6; ++i) {
      ca.src[2 + i] = (const float*)d_in[wsrc[i]];
      ca.dst[2 + i] = Wcv + (size_t)i * WELTS;
      ca.n[2 + i] = WELTS;
      ca.src[8 + i] = (const float*)d_in[wsrc[i] + 1];
      ca.dst[8 + i] = bcv + (size_t)i * 768;
      ca.n[8 + i] = 768;
    }
    if (big_ws) {
      ca.src[14] = (const float*)d_in[8];  ca.dst[14] = extraW;         ca.n[14] = WELTS;
      ca.src[15] = (const float*)d_in[16]; ca.dst[15] = extraW + WELTS; ca.n[15] = WELTS;
      ca.src[16] = (const float*)d_in[9];  ca.dst[16] = extraB;         ca.n[16] = 768;
      ca.src[17] = (const float*)d_in[17]; ca.dst[17] = extraB + 768;   ca.n[17] = 768;
      nseg = 18;
    }
    ca.flag = flag;
  }
  convert_inputs<<<dim3(512, nseg), dim3(256), 0, stream>>>(ca);

  GemmArgs gq;
  {
    const void* A6[6]  = {x, x, x, y, y, y};
    const void* Ac6[6] = {xb, xb, xb, yb, yb, yb};
    const int di[6] = {2, 4, 6, 10, 12, 14};
    bf16* C6[6] = {Qb, Kb, Vtb, Qdb, Kdb, Vtdb};
    for (int i = 0; i < 6; ++i) {
      gq.A[i] = A6[i]; gq.Ac[i] = Ac6[i];
      gq.W[i] = d_in[di[i]]; gq.Wc[i] = Wcv + (size_t)i * WELTS;
      gq.bias[i] = d_in[di[i] + 1]; gq.biasc[i] = bcv + (size_t)i * 768;
      gq.s0[i] = nullptr; gq.s1[i] = nullptr; gq.C[i] = C6[i];
      // Q, Qd pre-scaled by 1/sqrt(64) * log2(e) -> softmax in exp2 domain
      gq.cmul[i] = (i == 0 || i == 3) ? 0.18033688011112042f : 1.0f;
      gq.c_fixed[i] = 1; gq.ext_w[i] = 0; gq.out_elem_off[i] = 0;
      gq.vt[i] = (i == 2 || i == 5) ? 1 : 0;
    }
    gq.flag = flag;
  }
  gemm_bt<<<dim3(64, 6, 6), dim3(256), 0, stream>>>(gq);

  attn_mba<<<dim3(16, 96), dim3(256), 0, stream>>>(
      Qb, Kb, Vtb, Qdb, Kdb, Vtdb, d_in[18], d_in[19], d_in[20], d_in[21],
      ctxX, ctxY, flag);

  GemmArgs gp;
  for (int i = 0; i < 6; ++i) {
    gp.A[i] = ctxX; gp.Ac[i] = ctxX;
    gp.W[i] = d_in[8]; gp.Wc[i] = d_in[8];        // fp32 original when flag==0
    gp.bias[i] = d_in[9]; gp.biasc[i] = d_in[9];  // fp32 original when flag==0
    gp.s0[i] = d_in[18]; gp.s1[i] = d_in[19]; gp.C[i] = d_out;
    gp.cmul[i] = 1.0f; gp.c_fixed[i] = 0; gp.vt[i] = 0;
    gp.ext_w[i] = 1; gp.out_elem_off[i] = 0;
  }
  gp.A[1] = ctxY; gp.Ac[1] = ctxY;
  gp.W[1] = d_in[16]; gp.Wc[1] = d_in[16];
  gp.bias[1] = d_in[17]; gp.biasc[1] = d_in[17];
  gp.s0[1] = d_in[20]; gp.s1[1] = d_in[21];
  gp.out_elem_off[1] = (long long)ELTS;
  if (big_ws) {   // pre-converted bf16 projection weights/biases
    gp.Wc[0] = extraW;         gp.biasc[0] = extraB;       gp.ext_w[0] = 0;
    gp.Wc[1] = extraW + WELTS; gp.biasc[1] = extraB + 768; gp.ext_w[1] = 0;
  }
  gp.flag = flag;
  gemm_bt<<<dim3(64, 6, 2), dim3(256), 0, stream>>>(gp);
}

// Round 13
// 369.531 us; speedup vs baseline: 1.0634x; 1.0066x over previous
//
#include <hip/hip_runtime.h>

typedef __bf16 bf16;
typedef __bf16 bf16x8 __attribute__((ext_vector_type(8)));
typedef float f32x4 __attribute__((ext_vector_type(4)));

#define HD 768
#define ELTS 6291456   // 8*1024*768
#define WELTS 589824   // 768*768

__device__ __forceinline__ void gld_lds16(const bf16* g, bf16* l) {
  __builtin_amdgcn_global_load_lds((const __attribute__((address_space(1))) void*)g,
                                   (__attribute__((address_space(3))) void*)l, 16, 0, 0);
}

__device__ __forceinline__ float rdscalar(const void* p, int f) {
  return f ? (float)((const bf16*)p)[0] : ((const float*)p)[0];
}

__device__ __forceinline__ float exp2fast(float x) {
#if __has_builtin(__builtin_amdgcn_exp2f)
  return __builtin_amdgcn_exp2f(x);
#else
  return __builtin_exp2f(x);
#endif
}

__global__ void probe_dtype(const unsigned int* __restrict__ x, int* flag) {
  const int t = threadIdx.x;  // 64 threads
  int bad = 0;
#pragma unroll
  for (int i = 0; i < 4; ++i) {
    unsigned int wd = x[t * 4 + i];
    unsigned int e0 = (wd >> 7) & 0xFF;
    unsigned int e1 = (wd >> 23) & 0xFF;
    bad += (e0 >= 134) + (e1 >= 134);
  }
  unsigned long long m = __ballot(bad > 0);
  if (t == 0) *flag = (m == 0ULL) ? 1 : 0;   // 1 = bf16 inputs
}

// fp32 -> bf16 conversion (flag==0 only). QKV-side destinations live in d_out
// (consumed ONLY by the QKV GEMM, stream-ordered before the projection GEMM
// writes d_out). Projection W/bias destinations live in spare workspace when
// ws_size permits.
struct CvtArgs {
  const float* src[20];
  bf16* dst[20];
  int n[20];
  const int* flag;
};
__global__ __launch_bounds__(256) void convert_inputs(CvtArgs a) {
  if (*a.flag) return;
  const int seg = blockIdx.y;
  const float* s = a.src[seg];
  bf16* d = a.dst[seg];
  const int n4 = a.n[seg] >> 2;
  for (int i = blockIdx.x * blockDim.x + threadIdx.x; i < n4; i += gridDim.x * blockDim.x) {
    f32x4 v = *(const f32x4*)(s + i * 4);
    bf16 o[4];
#pragma unroll
    for (int e = 0; e < 4; ++e) o[e] = (bf16)v[e];
    *(unsigned long long*)(d + i * 4) = *(unsigned long long*)o;
  }
}

struct GemmArgs {
  const void* A[6];     // bf16 when flag==1
  const void* Ac[6];    // bf16 when flag==0 (converted / internal)
  const void* W[6];     // bf16 when flag==1
  const void* Wc[6];    // flag==0: bf16 converted (ext_w=0) or fp32 original (ext_w=1)
  const void* bias[6];  // bf16 when flag==1
  const void* biasc[6]; // flag==0: bf16 converted (ext_w=0) or fp32 original (ext_w=1)
  const void* s0[6];
  const void* s1[6];
  void* C[6];
  float cmul[6];        // epilogue scale on (acc + bias)
  int c_fixed[6];       // 1: C always internal bf16; 0: C dtype follows flag
  int vt[6];            // 1: write C transposed per-head: [b][h][d=64][s=1024]
  int ext_w[6];         // 1: when flag==0, W/bias are fp32 -> convert in-kernel
  long long out_elem_off[6];
  const int* flag;
};

// C[M=8192, N=768] = (A[M,768] @ W[N,768]^T + bias*bscale) * cmul
// BK=32 DOUBLE-BUFFERED prefetch loop (attn-proven pattern): stage(k+1) is
// issued BEFORE compute(k); the loads stay in flight across the entire
// compute phase and are drained by the (single) barrier of the next step.
// Previously the 1-phase loop put the full staging latency on the critical
// path of every k-step. LDS unchanged at 32 KB (2 x (8KB A + 8KB B)).
// Chunk swizzle: LDS[row][p] = global[row][p ^ (row&3)] (involution; applied
// on the pre-swizzled global source, linear gld_lds dest). Fragment read at
// chunk (l4 ^ (fr&3)) -> 8 lanes per 4-bank group = conflict-free minimum.
__global__ __launch_bounds__(256) void gemm_bt(GemmArgs args) {
  const int g = blockIdx.z;
  const int f = *args.flag;
  const bool c_bf = args.c_fixed[g] || f;
  const bool w_f32 = (!f) && args.ext_w[g];
  const bf16* __restrict__ A = (const bf16*)(f ? args.A[g] : args.Ac[g]);
  const void* __restrict__ Wp = f ? args.W[g] : args.Wc[g];
  const void* __restrict__ bias = f ? args.bias[g] : args.biasc[g];
  bf16* Cb = (bf16*)args.C[g] + args.out_elem_off[g];
  float* Cf = (float*)args.C[g] + args.out_elem_off[g];
  float bscale = 1.0f;
  if (args.s0[g]) bscale = rdscalar(args.s0[g], f) + rdscalar(args.s1[g], f);
  const float cmul = args.cmul[g];

  const int m0 = blockIdx.x * 128;
  const int n0 = blockIdx.y * 128;
  const int t = threadIdx.x;
  const int lane = t & 63;
  const int w = t >> 6;
  const int wm = (w >> 1) * 64, wn = (w & 1) * 64;

  // 2 buffers x (A 128x32 + B 128x32) = 32 KB
  __shared__ __attribute__((aligned(16))) bf16 As[2][128 * 32];
  __shared__ __attribute__((aligned(16))) bf16 Bs[2][128 * 32];

  f32x4 acc[4][4] = {};

  // staging map: chunk c = t (rows 0-63) and t+256 (rows 64-127); row = c>>2,
  // in-row position p = c&3. LDS dest linear (c*8). Global source chunk is
  // p ^ (row&3). row(t+256)&3 == row(t)&3, so one swizzled col per thread.
  const int row_s = t >> 2;                       // 0..63
  const int gswz = (((t & 3) ^ (row_s & 3)) << 3);

  const int fr = lane & 15;
  const int l4 = lane >> 4;
  const int sR = ((l4 ^ (fr & 3)) << 3);          // fragment chunk (swizzled)

  auto stageAB = [&](int kb) {
    const int buf = kb & 1;
    const int k0 = kb * 32;
    gld_lds16(A + (size_t)(m0 + row_s) * HD + k0 + gswz, &As[buf][t * 8]);
    gld_lds16(A + (size_t)(m0 + row_s + 64) * HD + k0 + gswz, &As[buf][(t + 256) * 8]);
    if (!w_f32) {
      gld_lds16((const bf16*)Wp + (size_t)(n0 + row_s) * HD + k0 + gswz, &Bs[buf][t * 8]);
      gld_lds16((const bf16*)Wp + (size_t)(n0 + row_s + 64) * HD + k0 + gswz, &Bs[buf][(t + 256) * 8]);
    } else {
      const float* Wf = (const float*)Wp;
#pragma unroll
      for (int i = 0; i < 2; ++i) {
        const int row = row_s + i * 64;
        const size_t src = (size_t)(n0 + row) * HD + k0 + gswz;
        f32x4 u0 = *(const f32x4*)(Wf + src), u1 = *(const f32x4*)(Wf + src + 4);
        bf16x8 v;
#pragma unroll
        for (int e = 0; e < 4; ++e) { v[e] = (bf16)u0[e]; v[e + 4] = (bf16)u1[e]; }
        *(bf16x8*)(&Bs[buf][(t + i * 256) * 8]) = v;
      }
    }
  };

  stageAB(0);
  __syncthreads();

  for (int kb = 0; kb < 24; ++kb) {
    if (kb) __syncthreads();          // stage(kb) landed; prev readers done
    if (kb + 1 < 24) stageAB(kb + 1); // prefetch flies across this compute
    const bf16* Ab = As[kb & 1];
    const bf16* Bb = Bs[kb & 1];
    bf16x8 af[4], bfr[4];
#pragma unroll
    for (int mi = 0; mi < 4; ++mi)
      af[mi] = *(const bf16x8*)(Ab + (wm + mi * 16 + fr) * 32 + sR);
#pragma unroll
    for (int ni = 0; ni < 4; ++ni)
      bfr[ni] = *(const bf16x8*)(Bb + (wn + ni * 16 + fr) * 32 + sR);
#pragma unroll
    for (int mi = 0; mi < 4; ++mi)
#pragma unroll
      for (int ni = 0; ni < 4; ++ni)
        acc[mi][ni] = __builtin_amdgcn_mfma_f32_16x16x32_bf16(af[mi], bfr[ni], acc[mi][ni], 0, 0, 0);
  }

  const int rq = (lane >> 4) * 4;
  const int is_vt = args.vt[g];
#pragma unroll
  for (int ni = 0; ni < 4; ++ni) {
    const int col = n0 + wn + ni * 16 + fr;
    const float bv = (w_f32 ? ((const float*)bias)[col]
                            : (float)((const bf16*)bias)[col]) * bscale;
#pragma unroll
    for (int mi = 0; mi < 4; ++mi) {
      const int row = m0 + wm + mi * 16 + rq;   // row % 4 == 0
      if (is_vt) {
        // 4 consecutive tokens (same bb, same d) -> one 8B store
        const int bb = row >> 10, s = row & 1023;
        const int hh = col >> 6, d = col & 63;
        bf16 tmp[4];
#pragma unroll
        for (int r = 0; r < 4; ++r) tmp[r] = (bf16)((acc[mi][ni][r] + bv) * cmul);
        *(unsigned long long*)(Cb + (((size_t)(bb * 12 + hh)) << 16) + (d << 10) + s) =
            *(const unsigned long long*)tmp;
      } else {
#pragma unroll
        for (int r = 0; r < 4; ++r) {
          const float val = (acc[mi][ni][r] + bv) * cmul;
          if (c_bf) Cb[(size_t)(row + r) * HD + col] = (bf16)val;
          else      Cf[(size_t)(row + r) * HD + col] = val;
        }
      }
    }
  }
}

// FUSED two-stream flash attention, SHIFT-FREE softmax — R12 version, FROZEN.
// K-merge + V-hoist (16 b128/wave-iter) at (256,2): 120.3us, no spill
// (VGPR 92, WRITE 24.6MB). R9 (24 reads, 3 blk/CU) also 120.3 -> structural
// plateau: LDS/VALU/MFMA/occupancy mutually balanced. Further edits trade
// one for another (8 rounds of evidence, R4-R12).
__global__ __launch_bounds__(256, 2) void attn_mba(
    const bf16* __restrict__ Q, const bf16* __restrict__ Kx, const bf16* __restrict__ Vtx,
    const bf16* __restrict__ Qd, const bf16* __restrict__ Kd, const bf16* __restrict__ Vtd,
    const void* w11, const void* w12, const void* w21, const void* w22,
    bf16* ctxX, bf16* ctxY, const int* flag) {
  // XCD-bijective swizzle (1536 = 8*192): each XCD gets 192 consecutive work
  // ids = 12 complete (bh) groups -> K/V L2-resident per XCD.
  const int linear = blockIdx.x + (blockIdx.y << 4);
  const int swz = (linear & 7) * 192 + (linear >> 3);
  const int qb = swz & 15;         // 0..15
  const int bh = swz >> 4;         // 0..95
  const int b = bh / 12;
  const int f = *flag;

  const float wgtX[2] = {rdscalar(w11, f), rdscalar(w12, f)};
  const float wgtY[2] = {rdscalar(w22, f), rdscalar(w21, f)};

  const size_t tok0 = (size_t)b * 1024;
  const size_t vbase = (size_t)bh * 65536;   // [bh][64][1024]
  const int fcol = (bh - b * 12) * 64;
  const int q0 = qb * 64;

  __shared__ __attribute__((aligned(16))) bf16 smem[16384];  // 32 KB
  bf16* Ks = smem;              // 2 x 4096: permuted keys x d (swizzled)
  bf16* Vs = smem + 8192;       // 2 x 4096: d x keys (swizzled)

  const int t = threadIdx.x, lane = t & 63, w = t >> 6;
  const int l15 = lane & 15, l4 = lane >> 4;

  // hoisted staging addresses (per-thread invariants; per-call adds kt only)
  const int g0 = t >> 3, slot0 = t & 7;
  const int g1 = g0 + 32;
  const int gs = (slot0 ^ (g0 & 7)) << 3;          // g1&7 == g0&7
  const int kp0 = (g0 & 32) + ((g0 & 12) << 1) + ((g0 & 16) >> 2) + (g0 & 3);
  const int kp1 = (g1 & 32) + ((g1 & 12) << 1) + ((g1 & 16) >> 2) + (g1 & 3);
  const size_t koffg0 = (tok0 + kp0) * HD + fcol + gs;
  const size_t koffg1 = (tok0 + kp1) * HD + fcol + gs;
  const size_t voffg0 = vbase + (size_t)g0 * 1024 + gs;
  const size_t voffg1 = vbase + (size_t)g1 * 1024 + gs;

  auto stage = [&](int nit) {
    const bf16* Kc = nit < 16 ? Kx : Kd;
    const bf16* Vc = nit < 16 ? Vtx : Vtd;
    const int kt64 = (nit & 15) * 64;
    bf16* Kb = Ks + (nit & 1) * 4096;
    bf16* Vb = Vs + (nit & 1) * 4096;
    gld_lds16(Kc + koffg0 + (size_t)kt64 * HD, Kb + t * 8);
    gld_lds16(Kc + koffg1 + (size_t)kt64 * HD, Kb + (t + 256) * 8);
    gld_lds16(Vc + voffg0 + kt64, Vb + t * 8);
    gld_lds16(Vc + voffg1 + kt64, Vb + (t + 256) * 8);
  };

  stage(0);

  // Q fragments direct from global (staging swizzle cancels for Q).
  const int qrow = w * 16 + l15;
  const bf16* qp0 = Q  + (tok0 + q0 + qrow) * HD + fcol;
  const bf16* qp1 = Qd + (tok0 + q0 + qrow) * HD + fcol;
  bf16x8 qf[2][2];
  qf[0][0] = *(const bf16x8*)(qp0 + (l4 << 3));
  qf[0][1] = *(const bf16x8*)(qp0 + ((4 + l4) << 3));
  qf[1][0] = *(const bf16x8*)(qp1 + (l4 << 3));
  qf[1][1] = *(const bf16x8*)(qp1 + ((4 + l4) << 3));

  // K/V fragment base: (mi*16+l15)&7 == l15&7, so the swizzle slot is
  // mi-independent; subtile mi at base + mi*1024, second half at ^32.
  const int kbase = l15 * 64 + ((l4 ^ (l15 & 7)) << 3);

  __syncthreads();   // first K/V staged

  f32x4 mixX[4] = {}, mixY[4] = {};
  f32x4 oacc[2][4] = {};
  f32x4 lsum[2] = {};          // per-lane partial row-sums

  for (int it = 0; it < 32; ++it) {
    if (it) __syncthreads();        // stage(it) landed; prev readers done
    if (it + 1 < 32) stage(it + 1); // prefetch flies across this compute
    const bf16* Kb = Ks + (it & 1) * 4096;
    const bf16* Vb = Vs + (it & 1) * 4096;

    // hoisted V fragment reads — 8 NAMED registers (stream-invariant; both
    // PVs consume them). (kbase+mi*1024)^32 == (kbase^32)+mi*1024.
    const bf16* vpa = Vb + kbase;
    const bf16* vpb = Vb + (kbase ^ 32);
    const bf16x8 va0 = *(const bf16x8*)(vpa);
    const bf16x8 va1 = *(const bf16x8*)(vpa + 1024);
    const bf16x8 va2 = *(const bf16x8*)(vpa + 2048);
    const bf16x8 va3 = *(const bf16x8*)(vpa + 3072);
    const bf16x8 vb0 = *(const bf16x8*)(vpb);
    const bf16x8 vb1 = *(const bf16x8*)(vpb + 1024);
    const bf16x8 vb2 = *(const bf16x8*)(vpb + 2048);
    const bf16x8 vb3 = *(const bf16x8*)(vpb + 3072);

    // ---- QK merged: each K fragment read ONCE, feeds both streams ----
    f32x4 sv0[4], sv1[4];
    __builtin_amdgcn_s_setprio(1);
#pragma unroll
    for (int mi = 0; mi < 4; ++mi) {
      const bf16x8 kf0 = *(const bf16x8*)(Kb + (kbase + mi * 1024));
      const bf16x8 kf1 = *(const bf16x8*)(Kb + ((kbase ^ 32) + mi * 1024));
      f32x4 a = {}, c = {};
      a = __builtin_amdgcn_mfma_f32_16x16x32_bf16(kf0, qf[0][0], a, 0, 0, 0);
      c = __builtin_amdgcn_mfma_f32_16x16x32_bf16(kf0, qf[1][0], c, 0, 0, 0);
      a = __builtin_amdgcn_mfma_f32_16x16x32_bf16(kf1, qf[0][1], a, 0, 0, 0);
      c = __builtin_amdgcn_mfma_f32_16x16x32_bf16(kf1, qf[1][1], c, 0, 0, 0);
      sv0[mi] = a; sv1[mi] = c;
    }
    __builtin_amdgcn_s_setprio(0);

    // stream-0 exp2 + repack FIRST (retires sv0 before sv1's exp2 -> lower
    // simultaneous register liveness)
    bf16x8 pf00, pf01;
    {
      f32x4 ls = lsum[0];
#pragma unroll
      for (int mi = 0; mi < 4; ++mi) {
        f32x4 e;
#pragma unroll
        for (int r = 0; r < 4; ++r) e[r] = exp2fast(sv0[mi][r]);
        sv0[mi] = e;
        ls += e;
      }
      lsum[0] = ls;
#pragma unroll
      for (int j = 0; j < 8; ++j) {
        pf00[j] = (bf16)sv0[(j >> 2)][j & 3];
        pf01[j] = (bf16)sv0[2 + (j >> 2)][j & 3];
      }
    }
    bf16x8 pf10, pf11;
    {
      f32x4 ls = lsum[1];
#pragma unroll
      for (int mi = 0; mi < 4; ++mi) {
        f32x4 e;
#pragma unroll
        for (int r = 0; r < 4; ++r) e[r] = exp2fast(sv1[mi][r]);
        sv1[mi] = e;
        ls += e;
      }
      lsum[1] = ls;
#pragma unroll
      for (int j = 0; j < 8; ++j) {
        pf10[j] = (bf16)sv1[(j >> 2)][j & 3];
        pf11[j] = (bf16)sv1[2 + (j >> 2)][j & 3];
      }
    }

    // ---- PV: 8 shared V regs feed both streams' accumulators ----
    __builtin_amdgcn_s_setprio(1);
    oacc[0][0] = __builtin_amdgcn_mfma_f32_16x16x32_bf16(va0, pf00, oacc[0][0], 0, 0, 0);
    oacc[1][0] = __builtin_amdgcn_mfma_f32_16x16x32_bf16(va0, pf10, oacc[1][0], 0, 0, 0);
    oacc[0][1] = __builtin_amdgcn_mfma_f32_16x16x32_bf16(va1, pf00, oacc[0][1], 0, 0, 0);
    oacc[1][1] = __builtin_amdgcn_mfma_f32_16x16x32_bf16(va1, pf10, oacc[1][1], 0, 0, 0);
    oacc[0][2] = __builtin_amdgcn_mfma_f32_16x16x32_bf16(va2, pf00, oacc[0][2], 0, 0, 0);
    oacc[1][2] = __builtin_amdgcn_mfma_f32_16x16x32_bf16(va2, pf10, oacc[1][2], 0, 0, 0);
    oacc[0][3] = __builtin_amdgcn_mfma_f32_16x16x32_bf16(va3, pf00, oacc[0][3], 0, 0, 0);
    oacc[1][3] = __builtin_amdgcn_mfma_f32_16x16x32_bf16(va3, pf10, oacc[1][3], 0, 0, 0);
    oacc[0][0] = __builtin_amdgcn_mfma_f32_16x16x32_bf16(vb0, pf01, oacc[0][0], 0, 0, 0);
    oacc[1][0] = __builtin_amdgcn_mfma_f32_16x16x32_bf16(vb0, pf11, oacc[1][0], 0, 0, 0);
    oacc[0][1] = __builtin_amdgcn_mfma_f32_16x16x32_bf16(vb1, pf01, oacc[0][1], 0, 0, 0);
    oacc[1][1] = __builtin_amdgcn_mfma_f32_16x16x32_bf16(vb1, pf11, oacc[1][1], 0, 0, 0);
    oacc[0][2] = __builtin_amdgcn_mfma_f32_16x16x32_bf16(vb2, pf01, oacc[0][2], 0, 0, 0);
    oacc[1][2] = __builtin_amdgcn_mfma_f32_16x16x32_bf16(vb2, pf11, oacc[1][2], 0, 0, 0);
    oacc[0][3] = __builtin_amdgcn_mfma_f32_16x16x32_bf16(vb3, pf01, oacc[0][3], 0, 0, 0);
    oacc[1][3] = __builtin_amdgcn_mfma_f32_16x16x32_bf16(vb3, pf11, oacc[1][3], 0, 0, 0);
    __builtin_amdgcn_s_setprio(0);

    if ((it & 15) == 15) {   // phase finalize: the ONLY cross-lane reduction
      const int ph = it >> 4;
      float l0 = (lsum[0][0] + lsum[0][1]) + (lsum[0][2] + lsum[0][3]);
      float l1 = (lsum[1][0] + lsum[1][1]) + (lsum[1][2] + lsum[1][3]);
      l0 += __shfl_xor(l0, 16); l0 += __shfl_xor(l0, 32);
      l1 += __shfl_xor(l1, 16); l1 += __shfl_xor(l1, 32);
      const float scX = wgtX[ph] / l0;
      const float scY = wgtY[ph] / l1;
#pragma unroll
      for (int mi = 0; mi < 4; ++mi) {
#pragma unroll
        for (int r = 0; r < 4; ++r) {
          mixX[mi][r] += scX * oacc[0][mi][r];
          mixY[mi][r] += scY * oacc[1][mi][r];
        }
        oacc[0][mi] = f32x4{};
        oacc[1][mi] = f32x4{};
      }
      lsum[0] = f32x4{};
      lsum[1] = f32x4{};
    }
  }

  // epilogue: transpose O^T -> O through LDS, coalesced b128 stores (both outs)
  __syncthreads();
  bf16* TX = smem;          // 64 x 72
  bf16* TY = smem + 4608;   // 64 x 72
#pragma unroll
  for (int mi = 0; mi < 4; ++mi)
#pragma unroll
    for (int r = 0; r < 4; ++r) {
      TX[qrow * 72 + mi * 16 + l4 * 4 + r] = (bf16)mixX[mi][r];
      TY[qrow * 72 + mi * 16 + l4 * 4 + r] = (bf16)mixY[mi][r];
    }
  __syncthreads();
#pragma unroll
  for (int i = 0; i < 2; ++i) {
    const int q = t + i * 256;
    const int g = q >> 3, dc = (q & 7) * 8;
    *(bf16x8*)(ctxX + (tok0 + q0 + g) * HD + fcol + dc) = *(const bf16x8*)(TX + g * 72 + dc);
    *(bf16x8*)(ctxY + (tok0 + q0 + g) * HD + fcol + dc) = *(const bf16x8*)(TY + g * 72 + dc);
  }
}

extern "C" void kernel_launch(void* const* d_in, const int* in_sizes, int n_in,
                              void* d_out, int out_size, void* d_ws, size_t ws_size,
                              hipStream_t stream) {
  (void)in_sizes; (void)n_in; (void)out_size;
  const void* x = d_in[0];
  const void* y = d_in[1];

  bf16* ws = (bf16*)d_ws;
  bf16* Qb   = ws + 0ull * ELTS;
  bf16* Kb   = ws + 1ull * ELTS;
  bf16* Vtb  = ws + 2ull * ELTS;   // [b][h][d][s]
  bf16* Qdb  = ws + 3ull * ELTS;
  bf16* Kdb  = ws + 4ull * ELTS;
  bf16* Vtdb = ws + 5ull * ELTS;
  bf16* ctxX = Qb;    // alias: safe (block-local read-then-write, disjoint slices)
  bf16* ctxY = Qdb;
  int* flag = (int*)(ws + 6ull * ELTS);

  // Projection W/bias bf16 scratch in spare workspace (survives until the proj
  // GEMM, untouched by QKV GEMM / attn). Runtime-guarded on ws_size.
  const size_t extra_elems = 6ull * ELTS + 32 + 2ull * WELTS + 2 * 768;
  const bool big_ws = ws_size >= extra_elems * sizeof(bf16);
  bf16* extraW = ws + 6ull * ELTS + 32;       // 2 x WELTS (Wo, Wod)
  bf16* extraB = extraW + 2ull * WELTS;       // 2 x 768   (bo, bod)

  // Conversion scratch in d_out — consumed ONLY by the QKV GEMM (stream-ordered
  // before any d_out write by the projection GEMM).
  bf16* cb = (bf16*)d_out;
  bf16* xb = cb;                              // ELTS
  bf16* yb = cb + (size_t)ELTS;               // ELTS
  bf16* Wcv = cb + 2ull * ELTS;               // 6 x WELTS (Wq,Wk,Wv,Wqd,Wkd,Wvd)
  bf16* bcv = Wcv + 6ull * WELTS;             // 6 x 768
  // total: 2*ELTS + 6*WELTS + 6*768 bf16 = 32.3 MB < 50.3 MB fp32 out region

  probe_dtype<<<dim3(1), dim3(64), 0, stream>>>((const unsigned int*)x, flag);

  CvtArgs ca;
  int nseg = 14;
  {
    const int wsrc[6] = {2, 4, 6, 10, 12, 14};   // QKV weights only
    ca.src[0] = (const float*)x;  ca.dst[0] = xb;  ca.n[0] = ELTS;
    ca.src[1] = (const float*)y;  ca.dst[1] = yb;  ca.n[1] = ELTS;
    for (int i = 0; i < 6; ++i) {
      ca.src[2 + i] = (const float*)d_in[wsrc[i]];
      ca.dst[2 + i] = Wcv + (size_t)i * WELTS;
      ca.n[2 + i] = WELTS;
      ca.src[8 + i] = (const float*)d_in[wsrc[i] + 1];
      ca.dst[8 + i] = bcv + (size_t)i * 768;
      ca.n[8 + i] = 768;
    }
    if (big_ws) {
      ca.src[14] = (const float*)d_in[8];  ca.dst[14] = extraW;         ca.n[14] = WELTS;
      ca.src[15] = (const float*)d_in[16]; ca.dst[15] = extraW + WELTS; ca.n[15] = WELTS;
      ca.src[16] = (const float*)d_in[9];  ca.dst[16] = extraB;         ca.n[16] = 768;
      ca.src[17] = (const float*)d_in[17]; ca.dst[17] = extraB + 768;   ca.n[17] = 768;
      nseg = 18;
    }
    ca.flag = flag;
  }
  convert_inputs<<<dim3(512, nseg), dim3(256), 0, stream>>>(ca);

  GemmArgs gq;
  {
    const void* A6[6]  = {x, x, x, y, y, y};
    const void* Ac6[6] = {xb, xb, xb, yb, yb, yb};
    const int di[6] = {2, 4, 6, 10, 12, 14};
    bf16* C6[6] = {Qb, Kb, Vtb, Qdb, Kdb, Vtdb};
    for (int i = 0; i < 6; ++i) {
      gq.A[i] = A6[i]; gq.Ac[i] = Ac6[i];
      gq.W[i] = d_in[di[i]]; gq.Wc[i] = Wcv + (size_t)i * WELTS;
      gq.bias[i] = d_in[di[i] + 1]; gq.biasc[i] = bcv + (size_t)i * 768;
      gq.s0[i] = nullptr; gq.s1[i] = nullptr; gq.C[i] = C6[i];
      // Q, Qd pre-scaled by 1/sqrt(64) * log2(e) -> softmax in exp2 domain
      gq.cmul[i] = (i == 0 || i == 3) ? 0.18033688011112042f : 1.0f;
      gq.c_fixed[i] = 1; gq.ext_w[i] = 0; gq.out_elem_off[i] = 0;
      gq.vt[i] = (i == 2 || i == 5) ? 1 : 0;
    }
    gq.flag = flag;
  }
  gemm_bt<<<dim3(64, 6, 6), dim3(256), 0, stream>>>(gq);

  attn_mba<<<dim3(16, 96), dim3(256), 0, stream>>>(
      Qb, Kb, Vtb, Qdb, Kdb, Vtdb, d_in[18], d_in[19], d_in[20], d_in[21],
      ctxX, ctxY, flag);

  GemmArgs gp;
  for (int i = 0; i < 6; ++i) {
    gp.A[i] = ctxX; gp.Ac[i] = ctxX;
    gp.W[i] = d_in[8]; gp.Wc[i] = d_in[8];        // fp32 original when flag==0
    gp.bias[i] = d_in[9]; gp.biasc[i] = d_in[9];  // fp32 original when flag==0
    gp.s0[i] = d_in[18]; gp.s1[i] = d_in[19]; gp.C[i] = d_out;
    gp.cmul[i] = 1.0f; gp.c_fixed[i] = 0; gp.vt[i] = 0;
    gp.ext_w[i] = 1; gp.out_elem_off[i] = 0;
  }
  gp.A[1] = ctxY; gp.Ac[1] = ctxY;
  gp.W[1] = d_in[16]; gp.Wc[1] = d_in[16];
  gp.bias[1] = d_in[17]; gp.biasc[1] = d_in[17];
  gp.s0[1] = d_in[20]; gp.s1[1] = d_in[21];
  gp.out_elem_off[1] = (long long)ELTS;
  if (big_ws) {   // pre-converted bf16 projection weights/biases
    gp.Wc[0] = extraW;         gp.biasc[0] = extraB;       gp.ext_w[0] = 0;
    gp.Wc[1] = extraW + WELTS; gp.biasc[1] = extraB + 768; gp.ext_w[1] = 0;
  }
  gp.flag = flag;
  gemm_bt<<<dim3(64, 6, 2), dim3(256), 0, stream>>>(gp);
}